// Round 4
// baseline (346.016 us; speedup 1.0000x reference)
//
#include <hip/hip_runtime.h>
#include <hip/hip_bf16.h>

typedef float f32x4 __attribute__((ext_vector_type(4)));
typedef short bfx8 __attribute__((ext_vector_type(8)));   // 8 bf16 in 4 VGPRs

typedef const __attribute__((address_space(1))) void* gvp;
typedef __attribute__((address_space(3))) void* lvp;

static __device__ __forceinline__ unsigned short f2bf(float f) {
    return __builtin_bit_cast(unsigned short, __float2bfloat16(f));
}

static __device__ __forceinline__ bfx8 cvt8(f32x4 lo, f32x4 hi) {
    bfx8 r;
    r[0] = (short)f2bf(lo[0]); r[1] = (short)f2bf(lo[1]);
    r[2] = (short)f2bf(lo[2]); r[3] = (short)f2bf(lo[3]);
    r[4] = (short)f2bf(hi[0]); r[5] = (short)f2bf(hi[1]);
    r[6] = (short)f2bf(hi[2]); r[7] = (short)f2bf(hi[3]);
    return r;
}

// ---------------------------------------------------------------------------
// Kernel 0: cast + transpose weights into WcatT[768][768] bf16.
// ---------------------------------------------------------------------------
__global__ void prep_w(const float* __restrict__ Wk, const float* __restrict__ Wq,
                       const float* __restrict__ Wv, unsigned short* __restrict__ WT) {
    const int n = blockIdx.x;       // 0..767
    const int e = threadIdx.x;      // 0..767
    const int which = n >> 8;
    const int h = n & 255;
    const float* W = (which == 0) ? Wq : (which == 1) ? Wk : Wv;
    WT[(size_t)n * 768 + e] = f2bf(W[(size_t)e * 256 + h]);
}

// ---------------------------------------------------------------------------
// Kernel 1: QKV = X @ [Wq|Wk|Wv].
//  - A fragments loaded DIRECTLY from global (f32 -> cvt8), no A-LDS:
//    cuts LDS read traffic 3x (was the measured bottleneck: 96KB/step vs
//    256B/clk port).
//  - B: 2x16KB double-buffered LDS, global_load_lds w16, pre-swizzled source
//    (^(row&7)<<4), T3-minimal pipeline: STAGE(next); compute(cur); barrier.
//  - XCD-remapped 1D grid (6 n-blocks of one X-tile consecutive on one XCD).
//  bn 0..3 (Q,K): out [t][h];  bn 4..5 (V): operand-swapped -> out V'[h][t]
// ---------------------------------------------------------------------------
__global__ __launch_bounds__(256) void qkv_gemm(const float* __restrict__ X,
                                                const unsigned short* __restrict__ WT,
                                                unsigned short* __restrict__ QKV) {
    __shared__ unsigned short Bb[2][128][64];   // 2 x 16KB, linear dest

    const int tid = threadIdx.x;
    const int bid = blockIdx.x;                    // 0..3071
    const int l   = (bid & 7) * 384 + (bid >> 3);  // bijective XCD remap
    const int bn  = l % 6;
    const int bm  = l / 6;
    const int m0 = bm * 128;
    const int n0 = bn * 128;
    const int w = tid >> 6, lane = tid & 63;
    const int wr = w >> 1, wc = w & 1;
    const int lrow = lane & 15, lhi = lane >> 4;
    const bool vswap = (bn >= 4);

    f32x4 acc[4][4];
    const f32x4 zero = {0.f, 0.f, 0.f, 0.f};
#pragma unroll
    for (int i = 0; i < 4; ++i)
#pragma unroll
        for (int j = 0; j < 4; ++j) acc[i][j] = zero;

    // per-wave A row pointers (rows m0 + wr*64 + mi*16 + lrow)
    const float* Arow[4];
#pragma unroll
    for (int mi = 0; mi < 4; ++mi)
        Arow[mi] = X + (size_t)(m0 + wr * 64 + mi * 16 + lrow) * 768;

    // ---- B staging: 4 x global_load_lds dwordx4, inverse-swizzled source
#define STAGE_B(kt, bs)                                                        \
    {                                                                          \
        const int k0s = (kt) * 64;                                             \
        _Pragma("unroll")                                                      \
        for (int i = 0; i < 4; ++i) {                                          \
            const int f = i * 256 + tid;                                       \
            const int row = f >> 3;                                            \
            const int cb  = (f & 7) * 16;                                      \
            const int cbs = cb ^ ((row & 7) << 4);                             \
            const unsigned short* g = WT + (size_t)(n0 + row) * 768 + k0s + (cbs >> 1); \
            char* lp = (char*)&Bb[bs][0][0] + i * 4096 + w * 1024;             \
            __builtin_amdgcn_global_load_lds((gvp)g, (lvp)lp, 16, 0, 0);       \
        }                                                                      \
    }

    STAGE_B(0, 0);
    __syncthreads();

    int cur = 0;
    for (int kt = 0; kt < 12; ++kt) {
        if (kt < 11) STAGE_B(kt + 1, cur ^ 1);
        const int k0 = kt * 64;
#pragma unroll
        for (int kk = 0; kk < 2; ++kk) {
            const int kb = kk * 32 + lhi * 8;            // elem col within K-step
            bfx8 a[4], bb4[4];
#pragma unroll
            for (int ni = 0; ni < 4; ++ni) {
                const int brow = wc * 64 + ni * 16 + lrow;
                const int s = (brow & 7) << 4;
                const char* bp = (const char*)&Bb[cur][brow][0];
                bb4[ni] = *(const bfx8*)(bp + ((kb << 1) ^ s));
            }
#pragma unroll
            for (int mi = 0; mi < 4; ++mi) {
                const float* p = Arow[mi] + k0 + kb;
                f32x4 lo = *(const f32x4*)(p);
                f32x4 hi = *(const f32x4*)(p + 4);
                a[mi] = cvt8(lo, hi);
            }
            if (!vswap) {
#pragma unroll
                for (int mi = 0; mi < 4; ++mi)
#pragma unroll
                    for (int ni = 0; ni < 4; ++ni)
                        acc[mi][ni] = __builtin_amdgcn_mfma_f32_16x16x32_bf16(
                            a[mi], bb4[ni], acc[mi][ni], 0, 0, 0);
            } else {
#pragma unroll
                for (int ni = 0; ni < 4; ++ni)
#pragma unroll
                    for (int mi = 0; mi < 4; ++mi)
                        acc[ni][mi] = __builtin_amdgcn_mfma_f32_16x16x32_bf16(
                            bb4[ni], a[mi], acc[ni][mi], 0, 0, 0);
            }
        }
        __syncthreads();   // drains stage DMA (vmcnt) + releases buffer cur
        cur ^= 1;
    }

    const int b = bm;
    if (!vswap) {
        const int which = bn >> 1;                         // 0=Q, 1=K
        const size_t base = ((size_t)(b * 3 + which)) << 15;
        const int hbase = (bn & 1) * 128;
#pragma unroll
        for (int mi = 0; mi < 4; ++mi)
#pragma unroll
            for (int ni = 0; ni < 4; ++ni) {
                const int t = wr * 64 + mi * 16 + lhi * 4;
                const int h = hbase + wc * 64 + ni * 16 + lrow;
#pragma unroll
                for (int j = 0; j < 4; ++j)
                    QKV[base + (size_t)(t + j) * 256 + h] = f2bf(acc[mi][ni][j]);
            }
    } else {
        const size_t base = ((size_t)(b * 3 + 2)) << 15;
#pragma unroll
        for (int ni = 0; ni < 4; ++ni)
#pragma unroll
            for (int mi = 0; mi < 4; ++mi) {
                const int h = (bn - 4) * 128 + wc * 64 + ni * 16 + lhi * 4;
                const int t = wr * 64 + mi * 16 + lrow;
#pragma unroll
                for (int j = 0; j < 4; ++j)
                    QKV[base + (size_t)(h + j) * 128 + t] = f2bf(acc[ni][mi][j]);
            }
    }
}

// ---------------------------------------------------------------------------
// Kernel 2: per-batch causal attention (unchanged — passing).
// ---------------------------------------------------------------------------
__global__ __launch_bounds__(512) void attn(const unsigned short* __restrict__ QKV,
                                            float* __restrict__ Out) {
    __shared__ unsigned short Kl[128][264];
    __shared__ unsigned short Vt[256][136];

    const int b = blockIdx.x;
    const int tid = threadIdx.x;
    const int w = tid >> 6, lane = tid & 63;
    const int lrow = lane & 15, lhi = lane >> 4;

    const unsigned short* Qb = QKV + ((size_t)(b * 3 + 0) << 15);
    const unsigned short* Kb = QKV + ((size_t)(b * 3 + 1) << 15);
    const unsigned short* Vb = QKV + ((size_t)(b * 3 + 2) << 15);

    const int t0 = w * 16;
    bfx8 aq[8];
#pragma unroll
    for (int kk = 0; kk < 8; ++kk)
        aq[kk] = *(const bfx8*)(Qb + (size_t)(t0 + lrow) * 256 + kk * 32 + lhi * 8);

#pragma unroll
    for (int i = 0; i < 8; ++i) {
        int f = i * 512 + tid;
        {
            int row = f >> 5, c = (f & 31) * 8;
            *(bfx8*)&Kl[row][c] = *(const bfx8*)(Kb + (size_t)row * 256 + c);
        }
        {
            int row = f >> 4, c = (f & 15) * 8;
            *(bfx8*)&Vt[row][c] = *(const bfx8*)(Vb + (size_t)row * 128 + c);
        }
    }
    __syncthreads();

    f32x4 sacc[8];
    const f32x4 zero = {0.f, 0.f, 0.f, 0.f};
#pragma unroll
    for (int sj = 0; sj < 8; ++sj) sacc[sj] = zero;
#pragma unroll
    for (int kk = 0; kk < 8; ++kk) {
        const int kb = kk * 32 + lhi * 8;
#pragma unroll
        for (int sj = 0; sj < 8; ++sj) {
            bfx8 bk = *(const bfx8*)&Kl[sj * 16 + lrow][kb];
            sacc[sj] = __builtin_amdgcn_mfma_f32_16x16x32_bf16(aq[kk], bk, sacc[sj], 0, 0, 0);
        }
    }

    const float scale = 0.03608439182435161f;   // 1/sqrt(768)
    float inv[4];
#pragma unroll
    for (int j = 0; j < 4; ++j) {
        const int t = t0 + lhi * 4 + j;
        float m = -1e30f;
#pragma unroll
        for (int sj = 0; sj < 8; ++sj) {
            int s = sj * 16 + lrow;
            float vv = sacc[sj][j] * scale;
            vv = (s <= t) ? vv : -1e30f;
            sacc[sj][j] = vv;
            m = fmaxf(m, vv);
        }
#pragma unroll
        for (int d = 1; d < 16; d <<= 1) m = fmaxf(m, __shfl_xor(m, d));
        float sum = 0.f;
#pragma unroll
        for (int sj = 0; sj < 8; ++sj) {
            float e = __expf(sacc[sj][j] - m);
            sacc[sj][j] = e;
            sum += e;
        }
#pragma unroll
        for (int d = 1; d < 16; d <<= 1) sum += __shfl_xor(sum, d);
        inv[j] = 1.0f / sum;
    }

    __syncthreads();

    unsigned short* Pl = &Kl[0][0] + (size_t)w * (16 * 136);
#pragma unroll
    for (int sj = 0; sj < 8; ++sj)
#pragma unroll
        for (int j = 0; j < 4; ++j)
            Pl[(lhi * 4 + j) * 136 + sj * 16 + lrow] = f2bf(sacc[sj][j] * inv[j]);

    bfx8 pa[4];
#pragma unroll
    for (int kk = 0; kk < 4; ++kk)
        pa[kk] = *(const bfx8*)(Pl + lrow * 136 + kk * 32 + lhi * 8);

    f32x4 oacc[16];
#pragma unroll
    for (int ni = 0; ni < 16; ++ni) oacc[ni] = zero;
#pragma unroll
    for (int ni = 0; ni < 16; ++ni) {
#pragma unroll
        for (int kk = 0; kk < 4; ++kk) {
            bfx8 bv = *(const bfx8*)&Vt[ni * 16 + lrow][kk * 32 + lhi * 8];
            oacc[ni] = __builtin_amdgcn_mfma_f32_16x16x32_bf16(pa[kk], bv, oacc[ni], 0, 0, 0);
        }
    }

    float* Ob = Out + (size_t)b * 128 * 256;
#pragma unroll
    for (int ni = 0; ni < 16; ++ni) {
#pragma unroll
        for (int j = 0; j < 4; ++j) {
            const int t = t0 + lhi * 4 + j;
            const int h = ni * 16 + lrow;
            Ob[(size_t)t * 256 + h] = oacc[ni][j];
        }
    }
}

// ---------------------------------------------------------------------------
extern "C" void kernel_launch(void* const* d_in, const int* in_sizes, int n_in,
                              void* d_out, int out_size, void* d_ws, size_t ws_size,
                              hipStream_t stream) {
    (void)in_sizes; (void)n_in; (void)out_size; (void)ws_size;
    const float* X  = (const float*)d_in[0];   // res_stream [512,128,768]
    const float* Wk = (const float*)d_in[1];   // [768,256]
    const float* Wq = (const float*)d_in[2];
    const float* Wv = (const float*)d_in[3];

    unsigned short* WT  = (unsigned short*)d_ws;          // 768*768 bf16
    unsigned short* QKV = WT + (size_t)768 * 768;         // 512*3*32768 bf16
    float* Out = (float*)d_out;

    prep_w<<<768, 768, 0, stream>>>(Wk, Wq, Wv, WT);
    qkv_gemm<<<3072, 256, 0, stream>>>(X, WT, QKV);
    attn<<<512, 512, 0, stream>>>(QKV, Out);
}

// Round 5
// 201.762 us; speedup vs baseline: 1.7150x; 1.7150x over previous
//
#include <hip/hip_runtime.h>
#include <hip/hip_bf16.h>

typedef float f32x4 __attribute__((ext_vector_type(4)));
typedef short bfx8 __attribute__((ext_vector_type(8)));   // 8 bf16 in 4 VGPRs

typedef const __attribute__((address_space(1))) void* gvp;
typedef __attribute__((address_space(3))) void* lvp;

static __device__ __forceinline__ unsigned short f2bf(float f) {
    return __builtin_bit_cast(unsigned short, __float2bfloat16(f));
}

static __device__ __forceinline__ ushort4 cvt4(f32x4 v) {
    return make_ushort4(f2bf(v[0]), f2bf(v[1]), f2bf(v[2]), f2bf(v[3]));
}

// ---------------------------------------------------------------------------
// Kernel 0: cast + transpose weights into WcatT[768][768] bf16.
// ---------------------------------------------------------------------------
__global__ void prep_w(const float* __restrict__ Wk, const float* __restrict__ Wq,
                       const float* __restrict__ Wv, unsigned short* __restrict__ WT) {
    const int n = blockIdx.x;       // 0..767
    const int e = threadIdx.x;      // 0..767
    const int which = n >> 8;
    const int h = n & 255;
    const float* W = (which == 0) ? Wq : (which == 1) ? Wk : Wv;
    WT[(size_t)n * 768 + e] = f2bf(W[(size_t)e * 256 + h]);
}

// ---------------------------------------------------------------------------
// Kernel 1: QKV = X @ [Wq|Wk|Wv].  Double-buffered 2-phase pipeline:
//  - A: reg-staged (coalesced float4) -> cvt to bf16 -> swizzled ds_write.
//       LDS A is bf16 [2][128][64] (16KB/buf): halves LDS read volume vs f32.
//  - B: global_load_lds w16, linear dest, pre-swizzled global source.
//  - XOR swizzle byte^=(row&7)<<4 on all LDS reads/writes (2-way max = free).
//  - One barrier per K-step; stage(kt+1) issued before compute(kt).
//  bn 0..3 (Q,K): out [t][h];  bn 4..5 (V): operand-swapped -> out V'[h][t]
// ---------------------------------------------------------------------------
__global__ __launch_bounds__(256, 2) void qkv_gemm(const float* __restrict__ X,
                                                   const unsigned short* __restrict__ WT,
                                                   unsigned short* __restrict__ QKV) {
    __shared__ unsigned short Ab[2][128][64];   // 2 x 16KB bf16
    __shared__ unsigned short Bb[2][128][64];   // 2 x 16KB bf16

    const int tid = threadIdx.x;
    const int bid = blockIdx.x;                    // 0..3071
    const int l   = (bid & 7) * 384 + (bid >> 3);  // bijective XCD remap
    const int bn  = l % 6;
    const int bm  = l / 6;
    const int m0 = bm * 128;
    const int n0 = bn * 128;
    const int w = tid >> 6, lane = tid & 63;
    const int wr = w >> 1, wc = w & 1;
    const int lrow = lane & 15, lhi = lane >> 4;
    const bool vswap = (bn >= 4);

    f32x4 acc[4][4];
    const f32x4 zero = {0.f, 0.f, 0.f, 0.f};
#pragma unroll
    for (int i = 0; i < 4; ++i)
#pragma unroll
        for (int j = 0; j < 4; ++j) acc[i][j] = zero;

    f32x4 areg[8];

    // ---- A: coalesced reg load (16 lanes x float4 = contiguous 256B)
#define STAGE_A_LOAD(kt)                                                       \
    {                                                                          \
        const int k0s = (kt) * 64;                                             \
        _Pragma("unroll")                                                      \
        for (int i = 0; i < 8; ++i) {                                          \
            const int f = i * 256 + tid;                                       \
            const int row = f >> 4, col = (f & 15) * 4;                        \
            areg[i] = *(const f32x4*)(X + (size_t)(m0 + row) * 768 + k0s + col); \
        }                                                                      \
    }
    // ---- A: cvt + swizzled ds_write_b64 (compiler inserts vmcnt for areg)
#define STAGE_A_WRITE(bs)                                                      \
    {                                                                          \
        _Pragma("unroll")                                                      \
        for (int i = 0; i < 8; ++i) {                                          \
            const int f = i * 256 + tid;                                       \
            const int row = f >> 4;                                            \
            const int cb  = (f & 15) * 8;                                      \
            const int cbs = cb ^ ((row & 7) << 4);                             \
            *(ushort4*)((char*)&Ab[bs][0][0] + row * 128 + cbs) = cvt4(areg[i]); \
        }                                                                      \
    }
    // ---- B: global_load_lds, inverse-swizzled source
#define STAGE_B(kt, bs)                                                        \
    {                                                                          \
        const int k0s = (kt) * 64;                                             \
        _Pragma("unroll")                                                      \
        for (int i = 0; i < 4; ++i) {                                          \
            const int f = i * 256 + tid;                                       \
            const int row = f >> 3;                                            \
            const int cb  = (f & 7) * 16;                                      \
            const int cbs = cb ^ ((row & 7) << 4);                             \
            const unsigned short* g = WT + (size_t)(n0 + row) * 768 + k0s + (cbs >> 1); \
            char* lp = (char*)&Bb[bs][0][0] + i * 4096 + w * 1024;             \
            __builtin_amdgcn_global_load_lds((gvp)g, (lvp)lp, 16, 0, 0);       \
        }                                                                      \
    }

    // prologue: fill buffer 0
    STAGE_B(0, 0);
    STAGE_A_LOAD(0);
    STAGE_A_WRITE(0);
    __syncthreads();

    int cur = 0;
    for (int kt = 0; kt < 12; ++kt) {
        if (kt < 11) {
            STAGE_B(kt + 1, cur ^ 1);
            STAGE_A_LOAD(kt + 1);
        }
#pragma unroll
        for (int kk = 0; kk < 2; ++kk) {
            const int kb2 = (kk * 32 + lhi * 8) * 2;       // byte col in 128B row
            bfx8 a[4], bb4[4];
#pragma unroll
            for (int mi = 0; mi < 4; ++mi) {
                const int arow = wr * 64 + mi * 16 + lrow;
                const char* ap = (const char*)&Ab[cur][arow][0];
                a[mi] = *(const bfx8*)(ap + (kb2 ^ ((arow & 7) << 4)));
            }
#pragma unroll
            for (int ni = 0; ni < 4; ++ni) {
                const int brow = wc * 64 + ni * 16 + lrow;
                const char* bp = (const char*)&Bb[cur][brow][0];
                bb4[ni] = *(const bfx8*)(bp + (kb2 ^ ((brow & 7) << 4)));
            }
            if (!vswap) {
#pragma unroll
                for (int mi = 0; mi < 4; ++mi)
#pragma unroll
                    for (int ni = 0; ni < 4; ++ni)
                        acc[mi][ni] = __builtin_amdgcn_mfma_f32_16x16x32_bf16(
                            a[mi], bb4[ni], acc[mi][ni], 0, 0, 0);
            } else {
#pragma unroll
                for (int ni = 0; ni < 4; ++ni)
#pragma unroll
                    for (int mi = 0; mi < 4; ++mi)
                        acc[ni][mi] = __builtin_amdgcn_mfma_f32_16x16x32_bf16(
                            bb4[ni], a[mi], acc[ni][mi], 0, 0, 0);
            }
        }
        if (kt < 11) STAGE_A_WRITE(cur ^ 1);
        __syncthreads();   // drains B DMA (vmcnt) + A ds_writes, releases cur
        cur ^= 1;
    }

    const int b = bm;
    if (!vswap) {
        const int which = bn >> 1;                         // 0=Q, 1=K
        const size_t base = ((size_t)(b * 3 + which)) << 15;
        const int hbase = (bn & 1) * 128;
#pragma unroll
        for (int mi = 0; mi < 4; ++mi)
#pragma unroll
            for (int ni = 0; ni < 4; ++ni) {
                const int t = wr * 64 + mi * 16 + lhi * 4;
                const int h = hbase + wc * 64 + ni * 16 + lrow;
#pragma unroll
                for (int j = 0; j < 4; ++j)
                    QKV[base + (size_t)(t + j) * 256 + h] = f2bf(acc[mi][ni][j]);
            }
    } else {
        const size_t base = ((size_t)(b * 3 + 2)) << 15;
#pragma unroll
        for (int ni = 0; ni < 4; ++ni)
#pragma unroll
            for (int mi = 0; mi < 4; ++mi) {
                const int h = (bn - 4) * 128 + wc * 64 + ni * 16 + lhi * 4;
                const int t = wr * 64 + mi * 16 + lrow;
#pragma unroll
                for (int j = 0; j < 4; ++j)
                    QKV[base + (size_t)(h + j) * 128 + t] = f2bf(acc[ni][mi][j]);
            }
    }
}

// ---------------------------------------------------------------------------
// Kernel 2: per-batch causal attention (unchanged — passing).
// ---------------------------------------------------------------------------
__global__ __launch_bounds__(512) void attn(const unsigned short* __restrict__ QKV,
                                            float* __restrict__ Out) {
    __shared__ unsigned short Kl[128][264];
    __shared__ unsigned short Vt[256][136];

    const int b = blockIdx.x;
    const int tid = threadIdx.x;
    const int w = tid >> 6, lane = tid & 63;
    const int lrow = lane & 15, lhi = lane >> 4;

    const unsigned short* Qb = QKV + ((size_t)(b * 3 + 0) << 15);
    const unsigned short* Kb = QKV + ((size_t)(b * 3 + 1) << 15);
    const unsigned short* Vb = QKV + ((size_t)(b * 3 + 2) << 15);

    const int t0 = w * 16;
    bfx8 aq[8];
#pragma unroll
    for (int kk = 0; kk < 8; ++kk)
        aq[kk] = *(const bfx8*)(Qb + (size_t)(t0 + lrow) * 256 + kk * 32 + lhi * 8);

#pragma unroll
    for (int i = 0; i < 8; ++i) {
        int f = i * 512 + tid;
        {
            int row = f >> 5, c = (f & 31) * 8;
            *(bfx8*)&Kl[row][c] = *(const bfx8*)(Kb + (size_t)row * 256 + c);
        }
        {
            int row = f >> 4, c = (f & 15) * 8;
            *(bfx8*)&Vt[row][c] = *(const bfx8*)(Vb + (size_t)row * 128 + c);
        }
    }
    __syncthreads();

    f32x4 sacc[8];
    const f32x4 zero = {0.f, 0.f, 0.f, 0.f};
#pragma unroll
    for (int sj = 0; sj < 8; ++sj) sacc[sj] = zero;
#pragma unroll
    for (int kk = 0; kk < 8; ++kk) {
        const int kb = kk * 32 + lhi * 8;
#pragma unroll
        for (int sj = 0; sj < 8; ++sj) {
            bfx8 bk = *(const bfx8*)&Kl[sj * 16 + lrow][kb];
            sacc[sj] = __builtin_amdgcn_mfma_f32_16x16x32_bf16(aq[kk], bk, sacc[sj], 0, 0, 0);
        }
    }

    const float scale = 0.03608439182435161f;   // 1/sqrt(768)
    float inv[4];
#pragma unroll
    for (int j = 0; j < 4; ++j) {
        const int t = t0 + lhi * 4 + j;
        float m = -1e30f;
#pragma unroll
        for (int sj = 0; sj < 8; ++sj) {
            int s = sj * 16 + lrow;
            float vv = sacc[sj][j] * scale;
            vv = (s <= t) ? vv : -1e30f;
            sacc[sj][j] = vv;
            m = fmaxf(m, vv);
        }
#pragma unroll
        for (int d = 1; d < 16; d <<= 1) m = fmaxf(m, __shfl_xor(m, d));
        float sum = 0.f;
#pragma unroll
        for (int sj = 0; sj < 8; ++sj) {
            float e = __expf(sacc[sj][j] - m);
            sacc[sj][j] = e;
            sum += e;
        }
#pragma unroll
        for (int d = 1; d < 16; d <<= 1) sum += __shfl_xor(sum, d);
        inv[j] = 1.0f / sum;
    }

    __syncthreads();

    unsigned short* Pl = &Kl[0][0] + (size_t)w * (16 * 136);
#pragma unroll
    for (int sj = 0; sj < 8; ++sj)
#pragma unroll
        for (int j = 0; j < 4; ++j)
            Pl[(lhi * 4 + j) * 136 + sj * 16 + lrow] = f2bf(sacc[sj][j] * inv[j]);

    bfx8 pa[4];
#pragma unroll
    for (int kk = 0; kk < 4; ++kk)
        pa[kk] = *(const bfx8*)(Pl + lrow * 136 + kk * 32 + lhi * 8);

    f32x4 oacc[16];
#pragma unroll
    for (int ni = 0; ni < 16; ++ni) oacc[ni] = zero;
#pragma unroll
    for (int ni = 0; ni < 16; ++ni) {
#pragma unroll
        for (int kk = 0; kk < 4; ++kk) {
            bfx8 bv = *(const bfx8*)&Vt[ni * 16 + lrow][kk * 32 + lhi * 8];
            oacc[ni] = __builtin_amdgcn_mfma_f32_16x16x32_bf16(pa[kk], bv, oacc[ni], 0, 0, 0);
        }
    }

    float* Ob = Out + (size_t)b * 128 * 256;
#pragma unroll
    for (int ni = 0; ni < 16; ++ni) {
#pragma unroll
        for (int j = 0; j < 4; ++j) {
            const int t = t0 + lhi * 4 + j;
            const int h = ni * 16 + lrow;
            Ob[(size_t)t * 256 + h] = oacc[ni][j];
        }
    }
}

// ---------------------------------------------------------------------------
extern "C" void kernel_launch(void* const* d_in, const int* in_sizes, int n_in,
                              void* d_out, int out_size, void* d_ws, size_t ws_size,
                              hipStream_t stream) {
    (void)in_sizes; (void)n_in; (void)out_size; (void)ws_size;
    const float* X  = (const float*)d_in[0];   // res_stream [512,128,768]
    const float* Wk = (const float*)d_in[1];   // [768,256]
    const float* Wq = (const float*)d_in[2];
    const float* Wv = (const float*)d_in[3];

    unsigned short* WT  = (unsigned short*)d_ws;          // 768*768 bf16
    unsigned short* QKV = WT + (size_t)768 * 768;         // 512*3*32768 bf16
    float* Out = (float*)d_out;

    prep_w<<<768, 768, 0, stream>>>(Wk, Wq, Wv, WT);
    qkv_gemm<<<3072, 256, 0, stream>>>(X, WT, QKV);
    attn<<<512, 512, 0, stream>>>(QKV, Out);
}